// Round 4
// baseline (1224.241 us; speedup 1.0000x reference)
//
#include <hip/hip_runtime.h>

#define NUU 100000
#define NII 50000
#define NEDGE 500000
#define NROWS (NII + NUU)          // combined CSR row count (items first, then users)

// Two-problem GEMM descriptor: out = A1@W1 (+ A2@W2) + bias, then
// mode 0 = none, 1 = relu, 2 = LayerNorm. In-place A1==out is SAFE here:
// each block stages/reads only its own 128-row tile (all 4 k-chunks) before
// its epilogue stores, and no other block touches those rows.
struct GemmP {
    const float* A1; const float* W1;
    const float* A2; const float* W2;
    const float* bias; const float* lg; const float* lb;
    float* out; float* nrm; int M; int mode;
};

// Tile 128 rows x 128 cols, 256 threads, thread = 8 rows x 8 cols
// (cols split-half: tx*4 and 64+tx*4). K chunked by 32.
// Optional fused row-L2-norm (nrm) and fused gumbel-hard head (pout).
__global__ __launch_bounds__(256, 3)
void gemm_dual(GemmP P0, GemmP P1, int gb0,
               const float* __restrict__ pw, const float* __restrict__ pb,
               const float* __restrict__ pu, float* __restrict__ pout)
{
    __shared__ float At[32][132];   // [k][row]
    __shared__ float Ws[32][132];   // [k][col]
    const bool sel = (blockIdx.x >= gb0);
    const GemmP P = sel ? P1 : P0;             // wave-uniform
    const int bi = sel ? (int)blockIdx.x - gb0 : (int)blockIdx.x;
    const int tid = threadIdx.x;
    const int tx = tid & 15;        // 16 col groups
    const int ty = tid >> 4;        // 16 row groups * 8 rows
    const int row0 = bi * 128;

    float acc[8][8];
#pragma unroll
    for (int i = 0; i < 8; ++i)
#pragma unroll
        for (int j = 0; j < 8; ++j) acc[i][j] = 0.f;

    const int nmat = (P.A2 != nullptr) ? 2 : 1;
    for (int m = 0; m < nmat; ++m) {
        const float* A = m ? P.A2 : P.A1;
        const float* W = m ? P.W2 : P.W1;
        for (int kc = 0; kc < 128; kc += 32) {
            __syncthreads();
            // stage A chunk: 128 rows x 32 k, transposed into At[k][row]
#pragma unroll
            for (int it = 0; it < 4; ++it) {
                int task = tid + 256 * it;       // 0..1023
                int r = task >> 3;               // 0..127
                int q = task & 7;                // float4 chunk of k
                int gr = row0 + r;
                float4 v = make_float4(0.f, 0.f, 0.f, 0.f);
                if (gr < P.M) v = *(const float4*)(A + (size_t)gr * 128 + kc + q * 4);
                At[q * 4 + 0][r] = v.x;
                At[q * 4 + 1][r] = v.y;
                At[q * 4 + 2][r] = v.z;
                At[q * 4 + 3][r] = v.w;
            }
            // stage W chunk: 32 k x 128 cols
#pragma unroll
            for (int it = 0; it < 4; ++it) {
                int task = tid + 256 * it;       // 0..1023
                int kr = task >> 5;              // 0..31
                int cq = task & 31;              // 0..31
                *(float4*)&Ws[kr][cq * 4] =
                    *(const float4*)(W + (size_t)(kc + kr) * 128 + cq * 4);
            }
            __syncthreads();
#pragma unroll 8
            for (int k = 0; k < 32; ++k) {
                float4 a0 = *(const float4*)&At[k][ty * 8];
                float4 a1 = *(const float4*)&At[k][ty * 8 + 4];
                float4 w0 = *(const float4*)&Ws[k][tx * 4];
                float4 w1 = *(const float4*)&Ws[k][64 + tx * 4];
                float a_[8] = {a0.x, a0.y, a0.z, a0.w, a1.x, a1.y, a1.z, a1.w};
                float w_[8] = {w0.x, w0.y, w0.z, w0.w, w1.x, w1.y, w1.z, w1.w};
#pragma unroll
                for (int i = 0; i < 8; ++i)
#pragma unroll
                    for (int j = 0; j < 8; ++j)
                        acc[i][j] += a_[i] * w_[j];
            }
        }
    }

    // epilogue: col(j) = j<4 ? tx*4+j : 64+tx*4+(j-4)
    float bv[8], lg[8], lb[8], paw0[8], paw1[8];
#pragma unroll
    for (int j = 0; j < 8; ++j) {
        int c = (j < 4) ? (tx * 4 + j) : (64 + tx * 4 + j - 4);
        bv[j] = P.bias[c];
        if (P.mode == 2) { lg[j] = P.lg[c]; lb[j] = P.lb[c]; }
        if (pout != nullptr) { paw0[j] = pw[c * 2]; paw1[j] = pw[c * 2 + 1]; }
    }
#pragma unroll
    for (int i = 0; i < 8; ++i) {
        int gr = row0 + ty * 8 + i;
        if (gr >= P.M) continue;   // uniform across each 16-lane tx group
        float v[8];
#pragma unroll
        for (int j = 0; j < 8; ++j) v[j] = acc[i][j] + bv[j];
        if (P.mode == 1) {
#pragma unroll
            for (int j = 0; j < 8; ++j) v[j] = fmaxf(v[j], 0.f);
        } else if (P.mode == 2) {
            float s = 0.f, sq = 0.f;
#pragma unroll
            for (int j = 0; j < 8; ++j) { s += v[j]; sq += v[j] * v[j]; }
#pragma unroll
            for (int msk = 1; msk < 16; msk <<= 1) {
                s += __shfl_xor(s, msk, 64);
                sq += __shfl_xor(sq, msk, 64);
            }
            float mean = s * (1.f / 128.f);
            float var = sq * (1.f / 128.f) - mean * mean;
            float inv = rsqrtf(var + 1e-5f);
#pragma unroll
            for (int j = 0; j < 8; ++j) v[j] = (v[j] - mean) * inv * lg[j] + lb[j];
        }
        if (pout != nullptr) {      // fused 128->2 head + gumbel-hard (enc launch)
            float q0 = 0.f, q1 = 0.f;
#pragma unroll
            for (int j = 0; j < 8; ++j) { q0 += v[j] * paw0[j]; q1 += v[j] * paw1[j]; }
#pragma unroll
            for (int msk = 1; msk < 16; msk <<= 1) {
                q0 += __shfl_xor(q0, msk, 64);
                q1 += __shfl_xor(q1, msk, 64);
            }
            if (tx == 0) {
                float l0 = q0 + pb[0], l1 = q1 + pb[1];
                float u0 = pu[2 * gr], u1 = pu[2 * gr + 1];
                float g0 = -logf(-logf(u0 * (1.f - 2e-6f) + 1e-6f));
                float g1 = -logf(-logf(u1 * (1.f - 2e-6f) + 1e-6f));
                float z0 = l0 + g0, z1 = l1 + g1;   // TAU = 1.0
                float mz = fmaxf(z0, z1);
                float e0 = expf(z0 - mz), e1 = expf(z1 - mz);
                float y0 = e0 / (e0 + e1);
                pout[gr] = (z0 >= z1) ? ((1.f - y0) + y0) : 0.f;  // fwd of (hard-y)+y
            }
        }
        if (P.nrm != nullptr) {     // fused row L2 norm (projection outputs)
            float sq = 0.f;
#pragma unroll
            for (int j = 0; j < 8; ++j) sq += v[j] * v[j];
#pragma unroll
            for (int msk = 1; msk < 16; msk <<= 1) sq += __shfl_xor(sq, msk, 64);
            if (tx == 0) P.nrm[gr] = fmaxf(sqrtf(sq), 1e-8f);
        }
        if (P.out != nullptr) {
            *(float4*)(P.out + (size_t)gr * 128 + tx * 4) = make_float4(v[0], v[1], v[2], v[3]);
            *(float4*)(P.out + (size_t)gr * 128 + 64 + tx * 4) = make_float4(v[4], v[5], v[6], v[7]);
        }
    }
}

// ------------- structural contrastive loss (half-wave per edge, float4 lanes) -------------
__global__ void loss_k(const float* __restrict__ hu, const float* __restrict__ hi,
                       const float* __restrict__ nu, const float* __restrict__ ni,
                       const int* __restrict__ src, const int* __restrict__ dst,
                       const int* __restrict__ uneg, const int* __restrict__ ineg,
                       float* __restrict__ loss, int ne)
{
    __shared__ float ls[8];
    int lane = threadIdx.x & 63;
    int half = lane >> 5;           // 0/1: which edge of the pair
    int l32 = lane & 31;
    int c4 = l32 * 4;               // 32 lanes x float4 = 128 cols
    int wib = threadIdx.x >> 6;
    int gw = (blockIdx.x * blockDim.x + threadIdx.x) >> 6;
    int nw = (gridDim.x * blockDim.x) >> 6;
    float part = 0.f;
    for (int ep = gw; ep < ne / 2; ep += nw) {   // ne is even
        int e = ep * 2 + half;
        int s = src[e], d = dst[e], un = uneg[e], in_ = ineg[e];
        float4 a = *(const float4*)(hu + (size_t)s * 128 + c4);
        float4 b = *(const float4*)(hi + (size_t)d * 128 + c4);
        float4 c = *(const float4*)(hi + (size_t)in_ * 128 + c4);
        float4 dd = *(const float4*)(hu + (size_t)un * 128 + c4);
        float p_sd = a.x * b.x + a.y * b.y + a.z * b.z + a.w * b.w;
        float p_sn = a.x * c.x + a.y * c.y + a.z * c.z + a.w * c.w;
        float p_nd = dd.x * b.x + dd.y * b.y + dd.z * b.z + dd.w * b.w;
#pragma unroll
        for (int m = 1; m < 32; m <<= 1) {        // reduce within half-wave
            p_sd += __shfl_xor(p_sd, m, 64);
            p_sn += __shfl_xor(p_sn, m, 64);
            p_nd += __shfl_xor(p_nd, m, 64);
        }
        if (l32 == 0) {
            float pos = p_sd / (nu[s] * ni[d]);
            float neg = p_sn / (nu[s] * ni[in_]) + p_nd / (nu[un] * ni[d]);
            float pe = expf(pos * 10.f);
            float nex = expf(neg * 10.f);
            part += -logf(pe / (pe + nex));
        }
    }
    if (l32 == 0) ls[wib * 2 + half] = part;
    __syncthreads();
    if (threadIdx.x == 0) {
        float t = 0.f;
#pragma unroll
        for (int j = 0; j < 8; ++j) t += ls[j];
        atomicAdd(loss, t * (1.f / 500000.f));
    }
}

// ---------------- CSR build (combined item||user row space) ----------------
__global__ void hist2_k(const int* __restrict__ ui_dst, const int* __restrict__ iu_dst,
                        int* __restrict__ deg)
{
    int e = blockIdx.x * blockDim.x + threadIdx.x;
    if (e < NEDGE) atomicAdd(&deg[ui_dst[e]], 1);                         // item rows
    else if (e < 2 * NEDGE) atomicAdd(&deg[NII + iu_dst[e - NEDGE]], 1);  // user rows
}

// 3-phase parallel exclusive scan over NROWS entries
__global__ void scan_part_k(const int* __restrict__ in, int* __restrict__ part, int N)
{
    __shared__ int wsum[4];
    int base = blockIdx.x * 1024 + threadIdx.x * 4;
    int s = 0;
    if (base + 3 < N) {
        int4 v = *(const int4*)(in + base);
        s = v.x + v.y + v.z + v.w;
    } else {
#pragma unroll
        for (int j = 0; j < 4; ++j) if (base + j < N) s += in[base + j];
    }
#pragma unroll
    for (int m = 1; m < 64; m <<= 1) s += __shfl_xor(s, m, 64);
    if ((threadIdx.x & 63) == 0) wsum[threadIdx.x >> 6] = s;
    __syncthreads();
    if (threadIdx.x == 0) part[blockIdx.x] = wsum[0] + wsum[1] + wsum[2] + wsum[3];
}

__global__ void scan_top_k(int* __restrict__ p, int nb)
{
    __shared__ int sm[256];
    int t = threadIdx.x;
    int v = (t < nb) ? p[t] : 0;
    sm[t] = v;
    __syncthreads();
    for (int o = 1; o < 256; o <<= 1) {
        int x = (t >= o) ? sm[t - o] : 0;
        __syncthreads();
        sm[t] += x;
        __syncthreads();
    }
    if (t < nb) p[t] = sm[t] - v;   // exclusive
}

__global__ void scan_final_k(const int* __restrict__ in, const int* __restrict__ part,
                             int* __restrict__ out, int N, int total)
{
    __shared__ int wtot[4];
    int tid = threadIdx.x;
    int lane = tid & 63, wid = tid >> 6;
    int base = blockIdx.x * 1024 + tid * 4;
    int v[4] = {0, 0, 0, 0};
    bool full = (base + 3 < N);
    if (full) {
        int4 q = *(const int4*)(in + base);
        v[0] = q.x; v[1] = q.y; v[2] = q.z; v[3] = q.w;
    } else {
#pragma unroll
        for (int j = 0; j < 4; ++j) if (base + j < N) v[j] = in[base + j];
    }
    int s = v[0] + v[1] + v[2] + v[3];
    int incl = s;
#pragma unroll
    for (int o = 1; o < 64; o <<= 1) {
        int n = __shfl_up(incl, o, 64);
        if (lane >= o) incl += n;
    }
    if (lane == 63) wtot[wid] = incl;
    __syncthreads();
    int woff = 0;
    for (int w2 = 0; w2 < wid; ++w2) woff += wtot[w2];
    int run = part[blockIdx.x] + woff + incl - s;   // exclusive offset for v[0]
    if (full) {
        int4 o4 = make_int4(run, run + v[0], run + v[0] + v[1], run + v[0] + v[1] + v[2]);
        *(int4*)(out + base) = o4;
    } else {
#pragma unroll
        for (int j = 0; j < 4; ++j) {
            if (base + j < N) { out[base + j] = run; run += v[j]; }
        }
    }
    if (blockIdx.x == 0 && tid == 0) out[N] = total;
}

__global__ void fill2_k(const int* __restrict__ ui_dst, const int* __restrict__ ui_src,
                        const int* __restrict__ iu_dst, const int* __restrict__ iu_src,
                        const int* __restrict__ rowstart, int* __restrict__ cursor,
                        int* __restrict__ elist)
{
    int e = blockIdx.x * blockDim.x + threadIdx.x;
    if (e < NEDGE) {
        int d = ui_dst[e];
        int p = atomicAdd(&cursor[d], 1);
        elist[rowstart[d] + p] = ui_src[e];
    } else if (e < 2 * NEDGE) {
        int d = NII + iu_dst[e - NEDGE];
        int p = atomicAdd(&cursor[d], 1);
        elist[rowstart[d] + p] = iu_src[e - NEDGE];
    }
}

// --- combined CSR aggregation over item||user rows (wave per dest row, 2 edges in
// flight via half-waves, float4 lanes). Items aggregate hu rows; users aggregate hi.
__global__ void agg_dual(const float* __restrict__ hu_c, const float* __restrict__ hi_c,
                         const int* __restrict__ rowstart, const int* __restrict__ elist,
                         float* __restrict__ hi_n, float* __restrict__ hu_n)
{
    int gt = blockIdx.x * blockDim.x + threadIdx.x;
    int w = gt >> 6, lane = gt & 63;
    if (w >= NROWS) return;
    const float* src;
    float* dst;
    if (w < NII) { src = hu_c; dst = hi_n + (size_t)w * 128; }
    else         { src = hi_c; dst = hu_n + (size_t)(w - NII) * 128; }
    int half = lane >> 5;
    int c4 = (lane & 31) * 4;
    int s0 = rowstart[w], s1 = rowstart[w + 1];
    float4 a = make_float4(0.f, 0.f, 0.f, 0.f);
    for (int e = s0 + half; e < s1; e += 2) {
        int s = elist[e];
        float4 v = *(const float4*)(src + (size_t)s * 128 + c4);
        a.x += v.x; a.y += v.y; a.z += v.z; a.w += v.w;
    }
    a.x += __shfl_xor(a.x, 32, 64);
    a.y += __shfl_xor(a.y, 32, 64);
    a.z += __shfl_xor(a.z, 32, 64);
    a.w += __shfl_xor(a.w, 32, 64);
    if (half == 0)
        *(float4*)(dst + c4) = a;
}

extern "C" void kernel_launch(void* const* d_in, const int* in_sizes, int n_in,
                              void* d_out, int out_size, void* d_ws, size_t ws_size,
                              hipStream_t stream)
{
    const float* x_user  = (const float*)d_in[0];
    const float* x_item  = (const float*)d_in[1];
    const float* u_user  = (const float*)d_in[3];
    const float* Wu_proj = (const float*)d_in[5];
    const float* bu_proj = (const float*)d_in[6];
    const float* Wi_proj = (const float*)d_in[7];
    const float* bi_proj = (const float*)d_in[8];
    const float* Wu_enc  = (const float*)d_in[9];
    const float* bu_enc  = (const float*)d_in[10];
    const float* Wu_act  = (const float*)d_in[11];
    const float* bu_act  = (const float*)d_in[12];
    // d_in[2,4,13..16] (item_pop, u_item, FairItemNet) are dead code in the reference
    const float* Wl_ui = (const float*)d_in[17];
    const float* Wr_ui = (const float*)d_in[18];
    const float* b_ui  = (const float*)d_in[19];
    const float* Wl_iu = (const float*)d_in[20];
    const float* Wr_iu = (const float*)d_in[21];
    const float* b_iu  = (const float*)d_in[22];
    const float* ln_u_g = (const float*)d_in[23];
    const float* ln_u_b = (const float*)d_in[24];
    const float* ln_i_g = (const float*)d_in[25];
    const float* ln_i_b = (const float*)d_in[26];
    const int* edge_ui  = (const int*)d_in[27];
    const int* edge_iu  = (const int*)d_in[28];
    const int* user_neg = (const int*)d_in[30];
    const int* item_neg = (const int*)d_in[31];

    float* out = (float*)d_out;
    // output layout: hu [NU*128] | hi [NI*128] | loss [1] | user_probs [NU]
    float* out_hu   = out;
    float* out_hi   = out + (size_t)NUU * 128;
    float* out_loss = out + 19200000;
    float* out_prob = out + 19200001;

    // workspace layout (~83 MB), all 16B-aligned
    float* hu0  = (float*)d_ws;
    float* hi0  = hu0 + (size_t)NUU * 128;
    float* nu   = hi0 + (size_t)NII * 128;
    float* ni   = nu + NUU;
    int* ip   = (int*)(ni + NII);
    int* rs   = ip;  ip += NROWS + 16;   // combined rowstart: items [0,NII], users [NII,NROWS]
    int* cur  = ip;  ip += NROWS;        // combined degree/cursor
    int* el   = ip;  ip += 2 * NEDGE;    // combined edge list (absolute offsets via rs)
    int* pt   = ip;  ip += 160;          // scan partials (147 used)

    const int* ui_src = edge_ui;           // users
    const int* ui_dst = edge_ui + NEDGE;   // items
    const int* iu_src = edge_iu;           // items
    const int* iu_dst = edge_iu + NEDGE;   // users

    const int GB_U = (NUU + 127) / 128, GB_I = (NII + 127) / 128;
    const int PB = (NROWS + 1023) / 1024;          // 147 scan blocks

    // projections user+item in one launch (+ fused row norms)
    GemmP pu_ = {x_user, Wu_proj, nullptr, nullptr, bu_proj, nullptr, nullptr, hu0, nu, NUU, 0};
    GemmP pi_ = {x_item, Wi_proj, nullptr, nullptr, bi_proj, nullptr, nullptr, hi0, ni, NII, 0};
    gemm_dual<<<GB_U + GB_I, 256, 0, stream>>>(pu_, pi_, GB_U, nullptr, nullptr, nullptr, nullptr);
    // encoder + fused gumbel-hard head (writes only user_probs)
    GemmP pe_ = {hu0, Wu_enc, nullptr, nullptr, bu_enc, nullptr, nullptr, nullptr, nullptr, NUU, 1};
    gemm_dual<<<GB_U, 256, 0, stream>>>(pe_, pe_, GB_U, Wu_act, bu_act, u_user, out_prob);
    // structural loss (reads hu0/hi0 + norms; must precede layer overwrites)
    hipMemsetAsync(out_loss, 0, 4, stream);
    loss_k<<<2048, 256, 0, stream>>>(hu0, hi0, nu, ni, ui_src, ui_dst, user_neg, item_neg, out_loss, NEDGE);
    // CSR build over combined row space (edge structure is layer-invariant)
    hipMemsetAsync(cur, 0, (size_t)NROWS * 4, stream);
    hist2_k<<<(2 * NEDGE + 255) / 256, 256, 0, stream>>>(ui_dst, iu_dst, cur);
    scan_part_k<<<PB, 256, 0, stream>>>(cur, pt, NROWS);
    scan_top_k<<<1, 256, 0, stream>>>(pt, PB);
    scan_final_k<<<PB, 256, 0, stream>>>(cur, pt, rs, NROWS, 2 * NEDGE);
    hipMemsetAsync(cur, 0, (size_t)NROWS * 4, stream);
    fill2_k<<<(2 * NEDGE + 255) / 256, 256, 0, stream>>>(ui_dst, ui_src, iu_dst, iu_src, rs, cur, el);

    // 3 hetero SAGE layers. agg writes straight into the next buffers; the layer
    // GEMM then runs in-place (A1 == out). Ping-pong ws <-> d_out so layer 2
    // lands in d_out.
    float* hu_c = hu0; float* hi_c = hi0;
    float* hu_n = out_hu; float* hi_n = out_hi;
    for (int l = 0; l < 3; ++l) {
        int mode = (l < 2) ? 2 : 0;   // LN on hidden layers only
        agg_dual<<<NROWS / 4, 256, 0, stream>>>(hu_c, hi_c, rs, el, hi_n, hu_n);
        GemmP li_ = {hi_n, Wl_ui + (size_t)l * 16384, hi_c, Wr_ui + (size_t)l * 16384,
                     b_ui + l * 128, ln_i_g + (l < 2 ? l : 0) * 128, ln_i_b + (l < 2 ? l : 0) * 128,
                     hi_n, nullptr, NII, mode};
        GemmP lu_ = {hu_n, Wl_iu + (size_t)l * 16384, hu_c, Wr_iu + (size_t)l * 16384,
                     b_iu + l * 128, ln_u_g + (l < 2 ? l : 0) * 128, ln_u_b + (l < 2 ? l : 0) * 128,
                     hu_n, nullptr, NUU, mode};
        gemm_dual<<<GB_I + GB_U, 256, 0, stream>>>(li_, lu_, GB_I, nullptr, nullptr, nullptr, nullptr);
        float* t;
        t = hu_c; hu_c = hu_n; hu_n = t;
        t = hi_c; hi_c = hi_n; hi_n = t;
    }
}

// Round 6
// 994.346 us; speedup vs baseline: 1.2312x; 1.2312x over previous
//
#include <hip/hip_runtime.h>

#define NUU 100000
#define NII 50000
#define NEDGE 500000
#define NROWS (NII + NUU)          // combined CSR row count (items first, then users)

typedef float f32x4 __attribute__((ext_vector_type(4)));
typedef short bf16x8 __attribute__((ext_vector_type(8)));

// Two-problem GEMM descriptor: out = A1@W1 (+ A2@W2) + bias, mode 0=none 1=relu 2=LN.
// W given as pre-split frag-ordered bf16 hi/lo planes. In-place A1==out is SAFE:
// each wave reads only its own 64-row slice (clamped rows resolve within the same
// block and feed only invalid rows) before its epilogue stores.
struct GemmP {
    const float* A1; const unsigned short* Wh1; const unsigned short* Wl1;
    const float* A2; const unsigned short* Wh2; const unsigned short* Wl2;
    const float* bias; const float* lg; const float* lb;
    float* out; float* nrm; int M; int mode;
};

// Split-bf16 MFMA GEMM. Block = 256 thr = 4 waves; tile 256 rows; wave = 64 rows
// (4 m-tiles of 16). Computes D = W^T h^T per 16x16x32 MFMA so each lane owns one
// output row with float4-contiguous columns. 3 MFMAs per tile-pair: hh + lh + hl.
__global__ __launch_bounds__(256, 2)
void gemm_dual(GemmP P0, GemmP P1, int gb0,
               const float* __restrict__ pw, const float* __restrict__ pb,
               const float* __restrict__ pu, float* __restrict__ pout)
{
    const bool sel = (blockIdx.x >= gb0);
    const GemmP P = sel ? P1 : P0;             // wave-uniform
    const int bi = sel ? (int)blockIdx.x - gb0 : (int)blockIdx.x;
    const int tid = threadIdx.x;
    const int l  = tid & 63;
    const int w  = tid >> 6;
    const int lm = l & 15;          // output row within 16-tile / W col
    const int lk = l >> 4;          // k-subgroup 0..3
    const int rowb = bi * 256 + w * 64;

    f32x4 acc[4][8];
#pragma unroll
    for (int mt = 0; mt < 4; ++mt)
#pragma unroll
        for (int nt = 0; nt < 8; ++nt) acc[mt][nt] = (f32x4){0.f, 0.f, 0.f, 0.f};

    const int nmat = (P.A2 != nullptr) ? 2 : 1;
    for (int m = 0; m < nmat; ++m) {
        const float* A = m ? P.A2 : P.A1;
        const unsigned short* Wh = m ? P.Wh2 : P.Wh1;
        const unsigned short* Wl = m ? P.Wl2 : P.Wl1;
#pragma unroll
        for (int kt = 0; kt < 4; ++kt) {
            // A-frags: lane reads 8 fp32 of row (rowb+mt*16+lm) at k = kt*32+lk*8,
            // exact-splits into bf16 hi/lo in registers.
            bf16x8 ah[4], al[4];
#pragma unroll
            for (int mt = 0; mt < 4; ++mt) {
                int row = rowb + mt * 16 + lm;
                int rowc = row < P.M ? row : P.M - 1;   // clamp: feeds only invalid rows
                const float* ap = A + (size_t)rowc * 128 + kt * 32 + lk * 8;
                float4 f0 = *(const float4*)ap;
                float4 f1 = *(const float4*)(ap + 4);
                float a8[8] = {f0.x, f0.y, f0.z, f0.w, f1.x, f1.y, f1.z, f1.w};
                union { bf16x8 v; unsigned int u[4]; } H, L;
#pragma unroll
                for (int p = 0; p < 4; ++p) {
                    unsigned int u0 = __float_as_uint(a8[2 * p]);
                    unsigned int u1 = __float_as_uint(a8[2 * p + 1]);
                    H.u[p] = (u0 >> 16) | (u1 & 0xffff0000u);
                    float l0 = a8[2 * p]     - __uint_as_float(u0 & 0xffff0000u);
                    float l1 = a8[2 * p + 1] - __uint_as_float(u1 & 0xffff0000u);
                    L.u[p] = (__float_as_uint(l0) >> 16) | (__float_as_uint(l1) & 0xffff0000u);
                }
                ah[mt] = H.v;
                al[mt] = L.v;
            }
            // B-frags (pre-split W planes) in two halves of 4 n-tiles to cap VGPRs
#pragma unroll
            for (int h = 0; h < 2; ++h) {
                bf16x8 bh[4], bl[4];
#pragma unroll
                for (int q = 0; q < 4; ++q) {
                    size_t fo = (size_t)((kt * 8 + h * 4 + q) * 64 + l) * 8;
                    bh[q] = *(const bf16x8*)(Wh + fo);
                    bl[q] = *(const bf16x8*)(Wl + fo);
                }
#pragma unroll
                for (int mt = 0; mt < 4; ++mt)
#pragma unroll
                    for (int q = 0; q < 4; ++q) {
                        int nt = h * 4 + q;
                        acc[mt][nt] = __builtin_amdgcn_mfma_f32_16x16x32_bf16(bh[q], ah[mt], acc[mt][nt], 0, 0, 0);
                        acc[mt][nt] = __builtin_amdgcn_mfma_f32_16x16x32_bf16(bl[q], ah[mt], acc[mt][nt], 0, 0, 0);
                        acc[mt][nt] = __builtin_amdgcn_mfma_f32_16x16x32_bf16(bh[q], al[mt], acc[mt][nt], 0, 0, 0);
                    }
            }
        }
    }

    // epilogue: lane holds row = rowb+mt*16+lm, col = nt*16+lk*4+i
    f32x4 bv[8];
#pragma unroll
    for (int nt = 0; nt < 8; ++nt)
        bv[nt] = *(const f32x4*)(P.bias + nt * 16 + lk * 4);

#pragma unroll
    for (int mt = 0; mt < 4; ++mt) {
        int row = rowb + mt * 16 + lm;
        bool valid = row < P.M;
        float v[8][4];
#pragma unroll
        for (int nt = 0; nt < 8; ++nt)
#pragma unroll
            for (int i = 0; i < 4; ++i) v[nt][i] = acc[mt][nt][i] + bv[nt][i];
        if (P.mode == 1) {
#pragma unroll
            for (int nt = 0; nt < 8; ++nt)
#pragma unroll
                for (int i = 0; i < 4; ++i) v[nt][i] = fmaxf(v[nt][i], 0.f);
        } else if (P.mode == 2) {
            float s = 0.f, sq = 0.f;
#pragma unroll
            for (int nt = 0; nt < 8; ++nt)
#pragma unroll
                for (int i = 0; i < 4; ++i) { s += v[nt][i]; sq += v[nt][i] * v[nt][i]; }
            s  += __shfl_xor(s, 16, 64);  s  += __shfl_xor(s, 32, 64);
            sq += __shfl_xor(sq, 16, 64); sq += __shfl_xor(sq, 32, 64);
            float mean = s * (1.f / 128.f);
            float var  = sq * (1.f / 128.f) - mean * mean;
            float inv  = rsqrtf(var + 1e-5f);
#pragma unroll
            for (int nt = 0; nt < 8; ++nt) {
                f32x4 lg = *(const f32x4*)(P.lg + nt * 16 + lk * 4);
                f32x4 lb = *(const f32x4*)(P.lb + nt * 16 + lk * 4);
#pragma unroll
                for (int i = 0; i < 4; ++i) v[nt][i] = (v[nt][i] - mean) * inv * lg[i] + lb[i];
            }
        }
        if (pout != nullptr) {      // fused 128->2 head + gumbel-hard (enc launch)
            float q0 = 0.f, q1 = 0.f;
#pragma unroll
            for (int nt = 0; nt < 8; ++nt) {
                const float* pp = pw + (size_t)(nt * 16 + lk * 4) * 2;
                f32x4 pa = *(const f32x4*)pp;
                f32x4 pc = *(const f32x4*)(pp + 4);
                q0 += v[nt][0] * pa[0] + v[nt][1] * pa[2] + v[nt][2] * pc[0] + v[nt][3] * pc[2];
                q1 += v[nt][0] * pa[1] + v[nt][1] * pa[3] + v[nt][2] * pc[1] + v[nt][3] * pc[3];
            }
            q0 += __shfl_xor(q0, 16, 64); q0 += __shfl_xor(q0, 32, 64);
            q1 += __shfl_xor(q1, 16, 64); q1 += __shfl_xor(q1, 32, 64);
            if (lk == 0 && valid) {
                float l0 = q0 + pb[0], l1 = q1 + pb[1];
                float u0 = pu[2 * row], u1 = pu[2 * row + 1];
                float g0 = -logf(-logf(u0 * (1.f - 2e-6f) + 1e-6f));
                float g1 = -logf(-logf(u1 * (1.f - 2e-6f) + 1e-6f));
                float z0 = l0 + g0, z1 = l1 + g1;   // TAU = 1.0
                float mz = fmaxf(z0, z1);
                float e0 = expf(z0 - mz), e1 = expf(z1 - mz);
                float y0 = e0 / (e0 + e1);
                pout[row] = (z0 >= z1) ? ((1.f - y0) + y0) : 0.f;  // fwd of (hard-y)+y
            }
        }
        if (P.nrm != nullptr) {     // fused row L2 norm (projection outputs)
            float sq = 0.f;
#pragma unroll
            for (int nt = 0; nt < 8; ++nt)
#pragma unroll
                for (int i = 0; i < 4; ++i) sq += v[nt][i] * v[nt][i];
            sq += __shfl_xor(sq, 16, 64); sq += __shfl_xor(sq, 32, 64);
            if (lk == 0 && valid) P.nrm[row] = fmaxf(sqrtf(sq), 1e-8f);
        }
        if (P.out != nullptr && valid) {
#pragma unroll
            for (int nt = 0; nt < 8; ++nt)
                *(float4*)(P.out + (size_t)row * 128 + nt * 16 + lk * 4) =
                    make_float4(v[nt][0], v[nt][1], v[nt][2], v[nt][3]);
        }
    }
}

// ---- weight pre-split: 15 matrices [128][128] fp32 -> frag-ordered bf16 hi/lo planes
struct WSrc { const float* p[7]; };
__global__ void wsplit_k(WSrc S, unsigned short* __restrict__ wout)
{
    int gid = blockIdx.x * 256 + threadIdx.x;
    if (gid >= 15 * 16384) return;
    int m = gid >> 14;
    int idx = gid & 16383;
    int k = idx >> 7, n = idx & 127;
    const float* src;
    if (m == 0) src = S.p[0];
    else if (m == 1) src = S.p[1];
    else if (m == 2) src = S.p[2];
    else if (m < 6)  src = S.p[3] + (size_t)(m - 3) * 16384;
    else if (m < 9)  src = S.p[4] + (size_t)(m - 6) * 16384;
    else if (m < 12) src = S.p[5] + (size_t)(m - 9) * 16384;
    else             src = S.p[6] + (size_t)(m - 12) * 16384;
    float wv = src[idx];
    unsigned int u = __float_as_uint(wv);
    unsigned short hi = (unsigned short)(u >> 16);
    float lof = wv - __uint_as_float(u & 0xffff0000u);
    unsigned short lo = (unsigned short)(__float_as_uint(lof) >> 16);
    int kt = k >> 5, kr = k & 31;
    int dst = ((kt * 8 + (n >> 4)) * 64 + ((kr >> 3) * 16 + (n & 15))) * 8 + (kr & 7);
    unsigned short* wm = wout + (size_t)m * 32768;
    wm[dst] = hi;
    wm[dst + 16384] = lo;
}

// ------------- structural contrastive loss (half-wave per edge, float4 lanes) -------------
__global__ void loss_k(const float* __restrict__ hu, const float* __restrict__ hi,
                       const float* __restrict__ nu, const float* __restrict__ ni,
                       const int* __restrict__ src, const int* __restrict__ dst,
                       const int* __restrict__ uneg, const int* __restrict__ ineg,
                       float* __restrict__ loss, int ne)
{
    __shared__ float ls[8];
    int lane = threadIdx.x & 63;
    int half = lane >> 5;           // 0/1: which edge of the pair
    int l32 = lane & 31;
    int c4 = l32 * 4;               // 32 lanes x float4 = 128 cols
    int wib = threadIdx.x >> 6;
    int gw = (blockIdx.x * blockDim.x + threadIdx.x) >> 6;
    int nw = (gridDim.x * blockDim.x) >> 6;
    float part = 0.f;
    for (int ep = gw; ep < ne / 2; ep += nw) {   // ne is even
        int e = ep * 2 + half;
        int s = src[e], d = dst[e], un = uneg[e], in_ = ineg[e];
        float4 a = *(const float4*)(hu + (size_t)s * 128 + c4);
        float4 b = *(const float4*)(hi + (size_t)d * 128 + c4);
        float4 c = *(const float4*)(hi + (size_t)in_ * 128 + c4);
        float4 dd = *(const float4*)(hu + (size_t)un * 128 + c4);
        float p_sd = a.x * b.x + a.y * b.y + a.z * b.z + a.w * b.w;
        float p_sn = a.x * c.x + a.y * c.y + a.z * c.z + a.w * c.w;
        float p_nd = dd.x * b.x + dd.y * b.y + dd.z * b.z + dd.w * b.w;
#pragma unroll
        for (int m = 1; m < 32; m <<= 1) {        // reduce within half-wave
            p_sd += __shfl_xor(p_sd, m, 64);
            p_sn += __shfl_xor(p_sn, m, 64);
            p_nd += __shfl_xor(p_nd, m, 64);
        }
        if (l32 == 0) {
            float pos = p_sd / (nu[s] * ni[d]);
            float neg = p_sn / (nu[s] * ni[in_]) + p_nd / (nu[un] * ni[d]);
            float pe = expf(pos * 10.f);
            float nex = expf(neg * 10.f);
            part += -logf(pe / (pe + nex));
        }
    }
    if (l32 == 0) ls[wib * 2 + half] = part;
    __syncthreads();
    if (threadIdx.x == 0) {
        float t = 0.f;
#pragma unroll
        for (int j = 0; j < 8; ++j) t += ls[j];
        atomicAdd(loss, t * (1.f / 500000.f));
    }
}

// ---------------- CSR build (combined item||user row space) ----------------
__global__ void hist2_k(const int* __restrict__ ui_dst, const int* __restrict__ iu_dst,
                        int* __restrict__ deg)
{
    int e = blockIdx.x * blockDim.x + threadIdx.x;
    if (e < NEDGE) atomicAdd(&deg[ui_dst[e]], 1);                         // item rows
    else if (e < 2 * NEDGE) atomicAdd(&deg[NII + iu_dst[e - NEDGE]], 1);  // user rows
}

// 3-phase parallel exclusive scan over NROWS entries
__global__ void scan_part_k(const int* __restrict__ in, int* __restrict__ part, int N)
{
    __shared__ int wsum[4];
    int base = blockIdx.x * 1024 + threadIdx.x * 4;
    int s = 0;
    if (base + 3 < N) {
        int4 v = *(const int4*)(in + base);
        s = v.x + v.y + v.z + v.w;
    } else {
#pragma unroll
        for (int j = 0; j < 4; ++j) if (base + j < N) s += in[base + j];
    }
#pragma unroll
    for (int m = 1; m < 64; m <<= 1) s += __shfl_xor(s, m, 64);
    if ((threadIdx.x & 63) == 0) wsum[threadIdx.x >> 6] = s;
    __syncthreads();
    if (threadIdx.x == 0) part[blockIdx.x] = wsum[0] + wsum[1] + wsum[2] + wsum[3];
}

__global__ void scan_top_k(int* __restrict__ p, int nb)
{
    __shared__ int sm[256];
    int t = threadIdx.x;
    int v = (t < nb) ? p[t] : 0;
    sm[t] = v;
    __syncthreads();
    for (int o = 1; o < 256; o <<= 1) {
        int x = (t >= o) ? sm[t - o] : 0;
        __syncthreads();
        sm[t] += x;
        __syncthreads();
    }
    if (t < nb) p[t] = sm[t] - v;   // exclusive
}

__global__ void scan_final_k(const int* __restrict__ in, const int* __restrict__ part,
                             int* __restrict__ out, int N, int total)
{
    __shared__ int wtot[4];
    int tid = threadIdx.x;
    int lane = tid & 63, wid = tid >> 6;
    int base = blockIdx.x * 1024 + tid * 4;
    int v[4] = {0, 0, 0, 0};
    bool full = (base + 3 < N);
    if (full) {
        int4 q = *(const int4*)(in + base);
        v[0] = q.x; v[1] = q.y; v[2] = q.z; v[3] = q.w;
    } else {
#pragma unroll
        for (int j = 0; j < 4; ++j) if (base + j < N) v[j] = in[base + j];
    }
    int s = v[0] + v[1] + v[2] + v[3];
    int incl = s;
#pragma unroll
    for (int o = 1; o < 64; o <<= 1) {
        int n = __shfl_up(incl, o, 64);
        if (lane >= o) incl += n;
    }
    if (lane == 63) wtot[wid] = incl;
    __syncthreads();
    int woff = 0;
    for (int w2 = 0; w2 < wid; ++w2) woff += wtot[w2];
    int run = part[blockIdx.x] + woff + incl - s;   // exclusive offset for v[0]
    if (full) {
        int4 o4 = make_int4(run, run + v[0], run + v[0] + v[1], run + v[0] + v[1] + v[2]);
        *(int4*)(out + base) = o4;
    } else {
#pragma unroll
        for (int j = 0; j < 4; ++j) {
            if (base + j < N) { out[base + j] = run; run += v[j]; }
        }
    }
    if (blockIdx.x == 0 && tid == 0) out[N] = total;
}

__global__ void fill2_k(const int* __restrict__ ui_dst, const int* __restrict__ ui_src,
                        const int* __restrict__ iu_dst, const int* __restrict__ iu_src,
                        const int* __restrict__ rowstart, int* __restrict__ cursor,
                        int* __restrict__ elist)
{
    int e = blockIdx.x * blockDim.x + threadIdx.x;
    if (e < NEDGE) {
        int d = ui_dst[e];
        int p = atomicAdd(&cursor[d], 1);
        elist[rowstart[d] + p] = ui_src[e];
    } else if (e < 2 * NEDGE) {
        int d = NII + iu_dst[e - NEDGE];
        int p = atomicAdd(&cursor[d], 1);
        elist[rowstart[d] + p] = iu_src[e - NEDGE];
    }
}

// --- combined CSR aggregation over item||user rows (wave per dest row, 2 edges in
// flight via half-waves, float4 lanes). Items aggregate hu rows; users aggregate hi.
__global__ void agg_dual(const float* __restrict__ hu_c, const float* __restrict__ hi_c,
                         const int* __restrict__ rowstart, const int* __restrict__ elist,
                         float* __restrict__ hi_n, float* __restrict__ hu_n)
{
    int gt = blockIdx.x * blockDim.x + threadIdx.x;
    int w = gt >> 6, lane = gt & 63;
    if (w >= NROWS) return;
    const float* src;
    float* dst;
    if (w < NII) { src = hu_c; dst = hi_n + (size_t)w * 128; }
    else         { src = hi_c; dst = hu_n + (size_t)(w - NII) * 128; }
    int half = lane >> 5;
    int c4 = (lane & 31) * 4;
    int s0 = rowstart[w], s1 = rowstart[w + 1];
    float4 a = make_float4(0.f, 0.f, 0.f, 0.f);
    for (int e = s0 + half; e < s1; e += 2) {
        int s = elist[e];
        float4 v = *(const float4*)(src + (size_t)s * 128 + c4);
        a.x += v.x; a.y += v.y; a.z += v.z; a.w += v.w;
    }
    a.x += __shfl_xor(a.x, 32, 64);
    a.y += __shfl_xor(a.y, 32, 64);
    a.z += __shfl_xor(a.z, 32, 64);
    a.w += __shfl_xor(a.w, 32, 64);
    if (half == 0)
        *(float4*)(dst + c4) = a;
}

extern "C" void kernel_launch(void* const* d_in, const int* in_sizes, int n_in,
                              void* d_out, int out_size, void* d_ws, size_t ws_size,
                              hipStream_t stream)
{
    const float* x_user  = (const float*)d_in[0];
    const float* x_item  = (const float*)d_in[1];
    const float* u_user  = (const float*)d_in[3];
    const float* Wu_proj = (const float*)d_in[5];
    const float* bu_proj = (const float*)d_in[6];
    const float* Wi_proj = (const float*)d_in[7];
    const float* bi_proj = (const float*)d_in[8];
    const float* Wu_enc  = (const float*)d_in[9];
    const float* bu_enc  = (const float*)d_in[10];
    const float* Wu_act  = (const float*)d_in[11];
    const float* bu_act  = (const float*)d_in[12];
    // d_in[2,4,13..16] (item_pop, u_item, FairItemNet) are dead code in the reference
    const float* Wl_ui = (const float*)d_in[17];
    const float* Wr_ui = (const float*)d_in[18];
    const float* b_ui  = (const float*)d_in[19];
    const float* Wl_iu = (const float*)d_in[20];
    const float* Wr_iu = (const float*)d_in[21];
    const float* b_iu  = (const float*)d_in[22];
    const float* ln_u_g = (const float*)d_in[23];
    const float* ln_u_b = (const float*)d_in[24];
    const float* ln_i_g = (const float*)d_in[25];
    const float* ln_i_b = (const float*)d_in[26];
    const int* edge_ui  = (const int*)d_in[27];
    const int* edge_iu  = (const int*)d_in[28];
    const int* user_neg = (const int*)d_in[30];
    const int* item_neg = (const int*)d_in[31];

    float* out = (float*)d_out;
    // output layout: hu [NU*128] | hi [NI*128] | loss [1] | user_probs [NU]
    float* out_hu   = out;
    float* out_hi   = out + (size_t)NUU * 128;
    float* out_loss = out + 19200000;
    float* out_prob = out + 19200001;

    // workspace layout (~85 MB), all 16B-aligned
    float* hu0  = (float*)d_ws;
    float* hi0  = hu0 + (size_t)NUU * 128;
    float* nu   = hi0 + (size_t)NII * 128;
    float* ni   = nu + NUU;
    int* ip   = (int*)(ni + NII);
    int* rs   = ip;  ip += NROWS + 16;   // combined rowstart: items [0,NII], users [NII,NROWS]
    int* cur  = ip;  ip += NROWS;        // combined degree/cursor
    int* el   = ip;  ip += 2 * NEDGE;    // combined edge list (absolute offsets via rs)
    int* pt   = ip;  ip += 160;          // scan partials (147 used)
    unsigned short* wsp = (unsigned short*)ip;   // 15 x (16384 hi + 16384 lo) bf16

    const int* ui_src = edge_ui;           // users
    const int* ui_dst = edge_ui + NEDGE;   // items
    const int* iu_src = edge_iu;           // items
    const int* iu_dst = edge_iu + NEDGE;   // users

    const int GB_U = (NUU + 255) / 256, GB_I = (NII + 255) / 256;   // 391 / 196
    const int PB = (NROWS + 1023) / 1024;          // 147 scan blocks

    // weight pre-split (frag-ordered bf16 hi/lo planes), every launch
    WSrc ws7 = {{Wu_proj, Wi_proj, Wu_enc, Wl_ui, Wr_ui, Wl_iu, Wr_iu}};
    wsplit_k<<<(15 * 16384 + 255) / 256, 256, 0, stream>>>(ws7, wsp);
    unsigned short* wm[15];
    for (int m = 0; m < 15; ++m) wm[m] = wsp + (size_t)m * 32768;

    // projections user+item in one launch (+ fused row norms)
    GemmP pu_ = {x_user, wm[0], wm[0] + 16384, nullptr, nullptr, nullptr,
                 bu_proj, nullptr, nullptr, hu0, nu, NUU, 0};
    GemmP pi_ = {x_item, wm[1], wm[1] + 16384, nullptr, nullptr, nullptr,
                 bi_proj, nullptr, nullptr, hi0, ni, NII, 0};
    gemm_dual<<<GB_U + GB_I, 256, 0, stream>>>(pu_, pi_, GB_U, nullptr, nullptr, nullptr, nullptr);
    // encoder + fused gumbel-hard head (writes only user_probs)
    GemmP pe_ = {hu0, wm[2], wm[2] + 16384, nullptr, nullptr, nullptr,
                 bu_enc, nullptr, nullptr, nullptr, nullptr, NUU, 1};
    gemm_dual<<<GB_U, 256, 0, stream>>>(pe_, pe_, GB_U, Wu_act, bu_act, u_user, out_prob);
    // structural loss (reads hu0/hi0 + norms; must precede layer overwrites)
    hipMemsetAsync(out_loss, 0, 4, stream);
    loss_k<<<2048, 256, 0, stream>>>(hu0, hi0, nu, ni, ui_src, ui_dst, user_neg, item_neg, out_loss, NEDGE);
    // CSR build over combined row space (edge structure is layer-invariant)
    hipMemsetAsync(cur, 0, (size_t)NROWS * 4, stream);
    hist2_k<<<(2 * NEDGE + 255) / 256, 256, 0, stream>>>(ui_dst, iu_dst, cur);
    scan_part_k<<<PB, 256, 0, stream>>>(cur, pt, NROWS);
    scan_top_k<<<1, 256, 0, stream>>>(pt, PB);
    scan_final_k<<<PB, 256, 0, stream>>>(cur, pt, rs, NROWS, 2 * NEDGE);
    hipMemsetAsync(cur, 0, (size_t)NROWS * 4, stream);
    fill2_k<<<(2 * NEDGE + 255) / 256, 256, 0, stream>>>(ui_dst, ui_src, iu_dst, iu_src, rs, cur, el);

    // 3 hetero SAGE layers. agg writes straight into the next buffers; the layer
    // GEMM then runs in-place (A1 == out). Ping-pong ws <-> d_out so layer 2
    // lands in d_out.
    float* hu_c = hu0; float* hi_c = hi0;
    float* hu_n = out_hu; float* hi_n = out_hi;
    for (int l = 0; l < 3; ++l) {
        int mode = (l < 2) ? 2 : 0;   // LN on hidden layers only
        agg_dual<<<NROWS / 4, 256, 0, stream>>>(hu_c, hi_c, rs, el, hi_n, hu_n);
        GemmP li_ = {hi_n, wm[3 + l], wm[3 + l] + 16384, hi_c, wm[6 + l], wm[6 + l] + 16384,
                     b_ui + l * 128, ln_i_g + (l < 2 ? l : 0) * 128, ln_i_b + (l < 2 ? l : 0) * 128,
                     hi_n, nullptr, NII, mode};
        GemmP lu_ = {hu_n, wm[9 + l], wm[9 + l] + 16384, hu_c, wm[12 + l], wm[12 + l] + 16384,
                     b_iu + l * 128, ln_u_g + (l < 2 ? l : 0) * 128, ln_u_b + (l < 2 ? l : 0) * 128,
                     hu_n, nullptr, NUU, mode};
        gemm_dual<<<GB_I + GB_U, 256, 0, stream>>>(li_, lu_, GB_I, nullptr, nullptr, nullptr, nullptr);
        float* t;
        t = hu_c; hu_c = hu_n; hu_n = t;
        t = hi_c; hi_c = hi_n; hi_n = t;
    }
}

// Round 9
// 879.332 us; speedup vs baseline: 1.3922x; 1.1308x over previous
//
#include <hip/hip_runtime.h>

#define NUU 100000
#define NII 50000
#define NEDGE 500000
#define NROWS (NII + NUU)          // combined CSR row count (items first, then users)

typedef float f32x4 __attribute__((ext_vector_type(4)));
typedef short bf16x8 __attribute__((ext_vector_type(8)));
typedef _Float16 half8v __attribute__((ext_vector_type(8)));
typedef _Float16 half4v __attribute__((ext_vector_type(4)));

// Two-problem GEMM descriptor: out = A1@W1 (+ A2@W2) + bias, mode 0=none 1=relu 2=LN.
// W given as pre-split frag-ordered bf16 hi/lo planes. In-place A1==out is SAFE:
// each wave reads only its own 64-row slice before its epilogue stores.
// out16: optional fp16 copy of the output rows (for downstream gathers).
struct GemmP {
    const float* A1; const unsigned short* Wh1; const unsigned short* Wl1;
    const float* A2; const unsigned short* Wh2; const unsigned short* Wl2;
    const float* bias; const float* lg; const float* lb;
    float* out; _Float16* out16; float* nrm; int M; int mode;
};

// Split-bf16 MFMA GEMM. Block = 256 thr = 4 waves; tile 256 rows; wave = 64 rows
// (4 m-tiles of 16). Computes D = W^T h^T per 16x16x32 MFMA so each lane owns one
// output row with float4-contiguous columns. 3 MFMAs per tile-pair: hh + lh + hl.
__global__ __launch_bounds__(256, 2)
void gemm_dual(GemmP P0, GemmP P1, int gb0,
               const float* __restrict__ pw, const float* __restrict__ pb,
               const float* __restrict__ pu, float* __restrict__ pout)
{
    const bool sel = (blockIdx.x >= gb0);
    const GemmP P = sel ? P1 : P0;             // wave-uniform
    const int bi = sel ? (int)blockIdx.x - gb0 : (int)blockIdx.x;
    const int tid = threadIdx.x;
    const int l  = tid & 63;
    const int w  = tid >> 6;
    const int lm = l & 15;          // output row within 16-tile / W col
    const int lk = l >> 4;          // k-subgroup 0..3
    const int rowb = bi * 256 + w * 64;

    f32x4 acc[4][8];
#pragma unroll
    for (int mt = 0; mt < 4; ++mt)
#pragma unroll
        for (int nt = 0; nt < 8; ++nt) acc[mt][nt] = (f32x4){0.f, 0.f, 0.f, 0.f};

    const int nmat = (P.A2 != nullptr) ? 2 : 1;
    for (int m = 0; m < nmat; ++m) {
        const float* A = m ? P.A2 : P.A1;
        const unsigned short* Wh = m ? P.Wh2 : P.Wh1;
        const unsigned short* Wl = m ? P.Wl2 : P.Wl1;
#pragma unroll
        for (int kt = 0; kt < 4; ++kt) {
            // A-frags: lane reads 8 fp32 of row (rowb+mt*16+lm) at k = kt*32+lk*8,
            // exact-splits into bf16 hi/lo in registers.
            bf16x8 ah[4], al[4];
#pragma unroll
            for (int mt = 0; mt < 4; ++mt) {
                int row = rowb + mt * 16 + lm;
                int rowc = row < P.M ? row : P.M - 1;   // clamp: feeds only invalid rows
                const float* ap = A + (size_t)rowc * 128 + kt * 32 + lk * 8;
                float4 f0 = *(const float4*)ap;
                float4 f1 = *(const float4*)(ap + 4);
                float a8[8] = {f0.x, f0.y, f0.z, f0.w, f1.x, f1.y, f1.z, f1.w};
                union { bf16x8 v; unsigned int u[4]; } H, L;
#pragma unroll
                for (int p = 0; p < 4; ++p) {
                    unsigned int u0 = __float_as_uint(a8[2 * p]);
                    unsigned int u1 = __float_as_uint(a8[2 * p + 1]);
                    H.u[p] = (u0 >> 16) | (u1 & 0xffff0000u);
                    float l0 = a8[2 * p]     - __uint_as_float(u0 & 0xffff0000u);
                    float l1 = a8[2 * p + 1] - __uint_as_float(u1 & 0xffff0000u);
                    L.u[p] = (__float_as_uint(l0) >> 16) | (__float_as_uint(l1) & 0xffff0000u);
                }
                ah[mt] = H.v;
                al[mt] = L.v;
            }
            // B-frags (pre-split W planes) in two halves of 4 n-tiles to cap VGPRs
#pragma unroll
            for (int h = 0; h < 2; ++h) {
                bf16x8 bh[4], bl[4];
#pragma unroll
                for (int q = 0; q < 4; ++q) {
                    size_t fo = (size_t)((kt * 8 + h * 4 + q) * 64 + l) * 8;
                    bh[q] = *(const bf16x8*)(Wh + fo);
                    bl[q] = *(const bf16x8*)(Wl + fo);
                }
#pragma unroll
                for (int mt = 0; mt < 4; ++mt)
#pragma unroll
                    for (int q = 0; q < 4; ++q) {
                        int nt = h * 4 + q;
                        acc[mt][nt] = __builtin_amdgcn_mfma_f32_16x16x32_bf16(bh[q], ah[mt], acc[mt][nt], 0, 0, 0);
                        acc[mt][nt] = __builtin_amdgcn_mfma_f32_16x16x32_bf16(bl[q], ah[mt], acc[mt][nt], 0, 0, 0);
                        acc[mt][nt] = __builtin_amdgcn_mfma_f32_16x16x32_bf16(bh[q], al[mt], acc[mt][nt], 0, 0, 0);
                    }
            }
        }
    }

    // epilogue: lane holds row = rowb+mt*16+lm, col = nt*16+lk*4+i
    f32x4 bv[8];
#pragma unroll
    for (int nt = 0; nt < 8; ++nt)
        bv[nt] = *(const f32x4*)(P.bias + nt * 16 + lk * 4);

#pragma unroll
    for (int mt = 0; mt < 4; ++mt) {
        int row = rowb + mt * 16 + lm;
        bool valid = row < P.M;
        float v[8][4];
#pragma unroll
        for (int nt = 0; nt < 8; ++nt)
#pragma unroll
            for (int i = 0; i < 4; ++i) v[nt][i] = acc[mt][nt][i] + bv[nt][i];
        if (P.mode == 1) {
#pragma unroll
            for (int nt = 0; nt < 8; ++nt)
#pragma unroll
                for (int i = 0; i < 4; ++i) v[nt][i] = fmaxf(v[nt][i], 0.f);
        } else if (P.mode == 2) {
            float s = 0.f, sq = 0.f;
#pragma unroll
            for (int nt = 0; nt < 8; ++nt)
#pragma unroll
                for (int i = 0; i < 4; ++i) { s += v[nt][i]; sq += v[nt][i] * v[nt][i]; }
            s  += __shfl_xor(s, 16, 64);  s  += __shfl_xor(s, 32, 64);
            sq += __shfl_xor(sq, 16, 64); sq += __shfl_xor(sq, 32, 64);
            float mean = s * (1.f / 128.f);
            float var  = sq * (1.f / 128.f) - mean * mean;
            float inv  = rsqrtf(var + 1e-5f);
#pragma unroll
            for (int nt = 0; nt < 8; ++nt) {
                f32x4 lg = *(const f32x4*)(P.lg + nt * 16 + lk * 4);
                f32x4 lb = *(const f32x4*)(P.lb + nt * 16 + lk * 4);
#pragma unroll
                for (int i = 0; i < 4; ++i) v[nt][i] = (v[nt][i] - mean) * inv * lg[i] + lb[i];
            }
        }
        if (pout != nullptr) {      // fused 128->2 head + gumbel-hard (enc launch)
            float q0 = 0.f, q1 = 0.f;
#pragma unroll
            for (int nt = 0; nt < 8; ++nt) {
                const float* pp = pw + (size_t)(nt * 16 + lk * 4) * 2;
                f32x4 pa = *(const f32x4*)pp;
                f32x4 pc = *(const f32x4*)(pp + 4);
                q0 += v[nt][0] * pa[0] + v[nt][1] * pa[2] + v[nt][2] * pc[0] + v[nt][3] * pc[2];
                q1 += v[nt][0] * pa[1] + v[nt][1] * pa[3] + v[nt][2] * pc[1] + v[nt][3] * pc[3];
            }
            q0 += __shfl_xor(q0, 16, 64); q0 += __shfl_xor(q0, 32, 64);
            q1 += __shfl_xor(q1, 16, 64); q1 += __shfl_xor(q1, 32, 64);
            if (lk == 0 && valid) {
                float l0 = q0 + pb[0], l1 = q1 + pb[1];
                float u0 = pu[2 * row], u1 = pu[2 * row + 1];
                float g0 = -logf(-logf(u0 * (1.f - 2e-6f) + 1e-6f));
                float g1 = -logf(-logf(u1 * (1.f - 2e-6f) + 1e-6f));
                float z0 = l0 + g0, z1 = l1 + g1;   // TAU = 1.0
                float mz = fmaxf(z0, z1);
                float e0 = expf(z0 - mz), e1 = expf(z1 - mz);
                float y0 = e0 / (e0 + e1);
                pout[row] = (z0 >= z1) ? ((1.f - y0) + y0) : 0.f;  // fwd of (hard-y)+y
            }
        }
        if (P.nrm != nullptr) {     // fused row L2 norm (projection outputs)
            float sq = 0.f;
#pragma unroll
            for (int nt = 0; nt < 8; ++nt)
#pragma unroll
                for (int i = 0; i < 4; ++i) sq += v[nt][i] * v[nt][i];
            sq += __shfl_xor(sq, 16, 64); sq += __shfl_xor(sq, 32, 64);
            if (lk == 0 && valid) P.nrm[row] = fmaxf(sqrtf(sq), 1e-8f);
        }
        if (valid) {
            if (P.out != nullptr) {
#pragma unroll
                for (int nt = 0; nt < 8; ++nt)
                    *(float4*)(P.out + (size_t)row * 128 + nt * 16 + lk * 4) =
                        make_float4(v[nt][0], v[nt][1], v[nt][2], v[nt][3]);
            }
            if (P.out16 != nullptr) {   // fp16 copy for downstream gathers
#pragma unroll
                for (int nt = 0; nt < 8; ++nt) {
                    half4v h;
#pragma unroll
                    for (int i = 0; i < 4; ++i) h[i] = (_Float16)v[nt][i];
                    *(half4v*)(P.out16 + (size_t)row * 128 + nt * 16 + lk * 4) = h;
                }
            }
        }
    }
}

// ---- weight pre-split: 15 matrices [128][128] fp32 -> frag-ordered bf16 hi/lo planes
struct WSrc { const float* p[7]; };
__global__ void wsplit_k(WSrc S, unsigned short* __restrict__ wout)
{
    int gid = blockIdx.x * 256 + threadIdx.x;
    if (gid >= 15 * 16384) return;
    int m = gid >> 14;
    int idx = gid & 16383;
    int k = idx >> 7, n = idx & 127;
    const float* src;
    if (m == 0) src = S.p[0];
    else if (m == 1) src = S.p[1];
    else if (m == 2) src = S.p[2];
    else if (m < 6)  src = S.p[3] + (size_t)(m - 3) * 16384;
    else if (m < 9)  src = S.p[4] + (size_t)(m - 6) * 16384;
    else if (m < 12) src = S.p[5] + (size_t)(m - 9) * 16384;
    else             src = S.p[6] + (size_t)(m - 12) * 16384;
    float wv = src[idx];
    unsigned int u = __float_as_uint(wv);
    unsigned short hi = (unsigned short)(u >> 16);
    float lof = wv - __uint_as_float(u & 0xffff0000u);
    unsigned short lo = (unsigned short)(__float_as_uint(lof) >> 16);
    int kt = k >> 5, kr = k & 31;
    int dst = ((kt * 8 + (n >> 4)) * 64 + ((kr >> 3) * 16 + (n & 15))) * 8 + (kr & 7);
    unsigned short* wm = wout + (size_t)m * 32768;
    wm[dst] = hi;
    wm[dst + 16384] = lo;
}

// ------- structural contrastive loss (quarter-wave per edge, half8 fp16 gathers) -------
__global__ void loss_k(const _Float16* __restrict__ hu16, const _Float16* __restrict__ hi16,
                       const float* __restrict__ nu, const float* __restrict__ ni,
                       const int* __restrict__ src, const int* __restrict__ dst,
                       const int* __restrict__ uneg, const int* __restrict__ ineg,
                       float* __restrict__ loss, int ne)
{
    __shared__ float ls[4];
    int lane = threadIdx.x & 63;
    int q = lane >> 4;              // quarter id: which edge of the 4
    int c8 = (lane & 15) * 8;       // 16 lanes x 8 halves = 128 cols
    int wib = threadIdx.x >> 6;
    int gw = (blockIdx.x * blockDim.x + threadIdx.x) >> 6;
    int nw = (gridDim.x * blockDim.x) >> 6;
    float part = 0.f;
    for (int eb = gw; eb < ne / 4; eb += nw) {   // ne divisible by 4
        int e = eb * 4 + q;
        int s = src[e], d = dst[e], un = uneg[e], in_ = ineg[e];
        half8v a = *(const half8v*)(hu16 + (size_t)s * 128 + c8);
        half8v b = *(const half8v*)(hi16 + (size_t)d * 128 + c8);
        half8v c = *(const half8v*)(hi16 + (size_t)in_ * 128 + c8);
        half8v dd = *(const half8v*)(hu16 + (size_t)un * 128 + c8);
        float p_sd = 0.f, p_sn = 0.f, p_nd = 0.f;
#pragma unroll
        for (int j = 0; j < 8; ++j) {
            float af = (float)a[j], bf = (float)b[j];
            p_sd += af * bf;
            p_sn += af * (float)c[j];
            p_nd += (float)dd[j] * bf;
        }
#pragma unroll
        for (int m = 1; m < 16; m <<= 1) {        // reduce within quarter-wave
            p_sd += __shfl_xor(p_sd, m, 64);
            p_sn += __shfl_xor(p_sn, m, 64);
            p_nd += __shfl_xor(p_nd, m, 64);
        }
        if ((lane & 15) == 0) {
            float pos = p_sd / (nu[s] * ni[d]);
            float neg = p_sn / (nu[s] * ni[in_]) + p_nd / (nu[un] * ni[d]);
            float pe = expf(pos * 10.f);
            float nex = expf(neg * 10.f);
            part += -logf(pe / (pe + nex));
        }
    }
    part += __shfl_xor(part, 16, 64);
    part += __shfl_xor(part, 32, 64);
    if (lane == 0) ls[wib] = part;
    __syncthreads();
    if (threadIdx.x == 0)
        atomicAdd(loss, (ls[0] + ls[1] + ls[2] + ls[3]) * (1.f / 500000.f));
}

// ---------------- CSR build (combined item||user row space) ----------------
__global__ void hist2_k(const int* __restrict__ ui_dst, const int* __restrict__ iu_dst,
                        int* __restrict__ deg)
{
    int e = blockIdx.x * blockDim.x + threadIdx.x;
    if (e < NEDGE) atomicAdd(&deg[ui_dst[e]], 1);                         // item rows
    else if (e < 2 * NEDGE) atomicAdd(&deg[NII + iu_dst[e - NEDGE]], 1);  // user rows
}

// 3-phase parallel exclusive scan over NROWS entries
__global__ void scan_part_k(const int* __restrict__ in, int* __restrict__ part, int N)
{
    __shared__ int wsum[4];
    int base = blockIdx.x * 1024 + threadIdx.x * 4;
    int s = 0;
    if (base + 3 < N) {
        int4 v = *(const int4*)(in + base);
        s = v.x + v.y + v.z + v.w;
    } else {
#pragma unroll
        for (int j = 0; j < 4; ++j) if (base + j < N) s += in[base + j];
    }
#pragma unroll
    for (int m = 1; m < 64; m <<= 1) s += __shfl_xor(s, m, 64);
    if ((threadIdx.x & 63) == 0) wsum[threadIdx.x >> 6] = s;
    __syncthreads();
    if (threadIdx.x == 0) part[blockIdx.x] = wsum[0] + wsum[1] + wsum[2] + wsum[3];
}

__global__ void scan_top_k(int* __restrict__ p, int nb)
{
    __shared__ int sm[256];
    int t = threadIdx.x;
    int v = (t < nb) ? p[t] : 0;
    sm[t] = v;
    __syncthreads();
    for (int o = 1; o < 256; o <<= 1) {
        int x = (t >= o) ? sm[t - o] : 0;
        __syncthreads();
        sm[t] += x;
        __syncthreads();
    }
    if (t < nb) p[t] = sm[t] - v;   // exclusive
}

__global__ void scan_final_k(const int* __restrict__ in, const int* __restrict__ part,
                             int* __restrict__ out, int N, int total)
{
    __shared__ int wtot[4];
    int tid = threadIdx.x;
    int lane = tid & 63, wid = tid >> 6;
    int base = blockIdx.x * 1024 + tid * 4;
    int v[4] = {0, 0, 0, 0};
    bool full = (base + 3 < N);
    if (full) {
        int4 q = *(const int4*)(in + base);
        v[0] = q.x; v[1] = q.y; v[2] = q.z; v[3] = q.w;
    } else {
#pragma unroll
        for (int j = 0; j < 4; ++j) if (base + j < N) v[j] = in[base + j];
    }
    int s = v[0] + v[1] + v[2] + v[3];
    int incl = s;
#pragma unroll
    for (int o = 1; o < 64; o <<= 1) {
        int n = __shfl_up(incl, o, 64);
        if (lane >= o) incl += n;
    }
    if (lane == 63) wtot[wid] = incl;
    __syncthreads();
    int woff = 0;
    for (int w2 = 0; w2 < wid; ++w2) woff += wtot[w2];
    int run = part[blockIdx.x] + woff + incl - s;   // exclusive offset for v[0]
    if (full) {
        int4 o4 = make_int4(run, run + v[0], run + v[0] + v[1], run + v[0] + v[1] + v[2]);
        *(int4*)(out + base) = o4;
    } else {
#pragma unroll
        for (int j = 0; j < 4; ++j) {
            if (base + j < N) { out[base + j] = run; run += v[j]; }
        }
    }
    if (blockIdx.x == 0 && tid == 0) out[N] = total;
}

__global__ void fill2_k(const int* __restrict__ ui_dst, const int* __restrict__ ui_src,
                        const int* __restrict__ iu_dst, const int* __restrict__ iu_src,
                        const int* __restrict__ rowstart, int* __restrict__ cursor,
                        int* __restrict__ elist)
{
    int e = blockIdx.x * blockDim.x + threadIdx.x;
    if (e < NEDGE) {
        int d = ui_dst[e];
        int p = atomicAdd(&cursor[d], 1);
        elist[rowstart[d] + p] = ui_src[e];
    } else if (e < 2 * NEDGE) {
        int d = NII + iu_dst[e - NEDGE];
        int p = atomicAdd(&cursor[d], 1);
        elist[rowstart[d] + p] = iu_src[e - NEDGE];
    }
}

// --- combined CSR aggregation (wave per dest row, 4 edges in flight via quarter-
// waves, half8 fp16 gathers, fp32 accumulate/write). Items sum hu16; users sum hi16.
__global__ void agg_dual(const _Float16* __restrict__ hu16, const _Float16* __restrict__ hi16,
                         const int* __restrict__ rowstart, const int* __restrict__ elist,
                         float* __restrict__ hi_n, float* __restrict__ hu_n)
{
    int gt = blockIdx.x * blockDim.x + threadIdx.x;
    int w = gt >> 6, lane = gt & 63;
    if (w >= NROWS) return;
    const _Float16* src;
    float* dst;
    if (w < NII) { src = hu16; dst = hi_n + (size_t)w * 128; }
    else         { src = hi16; dst = hu_n + (size_t)(w - NII) * 128; }
    int q = lane >> 4;
    int c8 = (lane & 15) * 8;
    int s0 = rowstart[w], s1 = rowstart[w + 1];
    float a[8] = {0.f, 0.f, 0.f, 0.f, 0.f, 0.f, 0.f, 0.f};
    for (int e = s0 + q; e < s1; e += 4) {
        int s = elist[e];
        half8v v = *(const half8v*)(src + (size_t)s * 128 + c8);
#pragma unroll
        for (int j = 0; j < 8; ++j) a[j] += (float)v[j];
    }
#pragma unroll
    for (int j = 0; j < 8; ++j) {
        a[j] += __shfl_xor(a[j], 16, 64);
        a[j] += __shfl_xor(a[j], 32, 64);
    }
    if (lane < 16) {
        *(float4*)(dst + c8)     = make_float4(a[0], a[1], a[2], a[3]);
        *(float4*)(dst + c8 + 4) = make_float4(a[4], a[5], a[6], a[7]);
    }
}

extern "C" void kernel_launch(void* const* d_in, const int* in_sizes, int n_in,
                              void* d_out, int out_size, void* d_ws, size_t ws_size,
                              hipStream_t stream)
{
    const float* x_user  = (const float*)d_in[0];
    const float* x_item  = (const float*)d_in[1];
    const float* u_user  = (const float*)d_in[3];
    const float* Wu_proj = (const float*)d_in[5];
    const float* bu_proj = (const float*)d_in[6];
    const float* Wi_proj = (const float*)d_in[7];
    const float* bi_proj = (const float*)d_in[8];
    const float* Wu_enc  = (const float*)d_in[9];
    const float* bu_enc  = (const float*)d_in[10];
    const float* Wu_act  = (const float*)d_in[11];
    const float* bu_act  = (const float*)d_in[12];
    // d_in[2,4,13..16] (item_pop, u_item, FairItemNet) are dead code in the reference
    const float* Wl_ui = (const float*)d_in[17];
    const float* Wr_ui = (const float*)d_in[18];
    const float* b_ui  = (const float*)d_in[19];
    const float* Wl_iu = (const float*)d_in[20];
    const float* Wr_iu = (const float*)d_in[21];
    const float* b_iu  = (const float*)d_in[22];
    const float* ln_u_g = (const float*)d_in[23];
    const float* ln_u_b = (const float*)d_in[24];
    const float* ln_i_g = (const float*)d_in[25];
    const float* ln_i_b = (const float*)d_in[26];
    const int* edge_ui  = (const int*)d_in[27];
    const int* edge_iu  = (const int*)d_in[28];
    const int* user_neg = (const int*)d_in[30];
    const int* item_neg = (const int*)d_in[31];

    float* out = (float*)d_out;
    // output layout: hu [NU*128] | hi [NI*128] | loss [1] | user_probs [NU]
    float* out_hu   = out;
    float* out_hi   = out + (size_t)NUU * 128;
    float* out_loss = out + 19200000;
    float* out_prob = out + 19200001;

    // workspace layout (~122 MB), all 16B-aligned
    float* hu0  = (float*)d_ws;
    float* hi0  = hu0 + (size_t)NUU * 128;
    float* nu   = hi0 + (size_t)NII * 128;
    float* ni   = nu + NUU;
    int* ip   = (int*)(ni + NII);
    int* rs   = ip;  ip += NROWS + 16;   // combined rowstart: items [0,NII], users [NII,NROWS]
    int* cur  = ip;  ip += NROWS;        // combined degree/cursor
    int* el   = ip;  ip += 2 * NEDGE;    // combined edge list (absolute offsets via rs)
    int* pt   = ip;  ip += 160;          // scan partials (147 used)
    unsigned short* wsp = (unsigned short*)ip;   // 15 x (16384 hi + 16384 lo) bf16
    _Float16* hu16 = (_Float16*)(wsp + 15 * 32768);   // fp16 gather copies
    _Float16* hi16 = hu16 + (size_t)NUU * 128;

    const int* ui_src = edge_ui;           // users
    const int* ui_dst = edge_ui + NEDGE;   // items
    const int* iu_src = edge_iu;           // items
    const int* iu_dst = edge_iu + NEDGE;   // users

    const int GB_U = (NUU + 255) / 256, GB_I = (NII + 255) / 256;   // 391 / 196
    const int PB = (NROWS + 1023) / 1024;          // 147 scan blocks

    // weight pre-split (frag-ordered bf16 hi/lo planes), every launch
    WSrc ws7 = {{Wu_proj, Wi_proj, Wu_enc, Wl_ui, Wr_ui, Wl_iu, Wr_iu}};
    wsplit_k<<<(15 * 16384 + 255) / 256, 256, 0, stream>>>(ws7, wsp);
    unsigned short* wm[15];
    for (int m = 0; m < 15; ++m) wm[m] = wsp + (size_t)m * 32768;

    // projections user+item in one launch (+ fused row norms + fp16 copies)
    GemmP pu_ = {x_user, wm[0], wm[0] + 16384, nullptr, nullptr, nullptr,
                 bu_proj, nullptr, nullptr, hu0, hu16, nu, NUU, 0};
    GemmP pi_ = {x_item, wm[1], wm[1] + 16384, nullptr, nullptr, nullptr,
                 bi_proj, nullptr, nullptr, hi0, hi16, ni, NII, 0};
    gemm_dual<<<GB_U + GB_I, 256, 0, stream>>>(pu_, pi_, GB_U, nullptr, nullptr, nullptr, nullptr);
    // encoder + fused gumbel-hard head (writes only user_probs; fp32 path)
    GemmP pe_ = {hu0, wm[2], wm[2] + 16384, nullptr, nullptr, nullptr,
                 bu_enc, nullptr, nullptr, nullptr, nullptr, nullptr, NUU, 1};
    gemm_dual<<<GB_U, 256, 0, stream>>>(pe_, pe_, GB_U, Wu_act, bu_act, u_user, out_prob);
    // structural loss (fp16 gathers from proj copies; must precede layer overwrites)
    hipMemsetAsync(out_loss, 0, 4, stream);
    loss_k<<<2048, 256, 0, stream>>>(hu16, hi16, nu, ni, ui_src, ui_dst, user_neg, item_neg, out_loss, NEDGE);
    // CSR build over combined row space (edge structure is layer-invariant)
    hipMemsetAsync(cur, 0, (size_t)NROWS * 4, stream);
    hist2_k<<<(2 * NEDGE + 255) / 256, 256, 0, stream>>>(ui_dst, iu_dst, cur);
    scan_part_k<<<PB, 256, 0, stream>>>(cur, pt, NROWS);
    scan_top_k<<<1, 256, 0, stream>>>(pt, PB);
    scan_final_k<<<PB, 256, 0, stream>>>(cur, pt, rs, NROWS, 2 * NEDGE);
    hipMemsetAsync(cur, 0, (size_t)NROWS * 4, stream);
    fill2_k<<<(2 * NEDGE + 255) / 256, 256, 0, stream>>>(ui_dst, ui_src, iu_dst, iu_src, rs, cur, el);

    // 3 hetero SAGE layers. agg gathers fp16 copies, writes fp32 into h_n; the
    // layer GEMM runs in-place on h_n (A1 == out) and refreshes the fp16 copies
    // (layers 0,1 only — layer 2 has no consumer). Ping-pong ws <-> d_out.
    float* hu_c = hu0; float* hi_c = hi0;
    float* hu_n = out_hu; float* hi_n = out_hi;
    for (int l = 0; l < 3; ++l) {
        int mode = (l < 2) ? 2 : 0;   // LN on hidden layers only
        agg_dual<<<NROWS / 4, 256, 0, stream>>>(hu16, hi16, rs, el, hi_n, hu_n);
        GemmP li_ = {hi_n, wm[3 + l], wm[3 + l] + 16384, hi_c, wm[6 + l], wm[6 + l] + 16384,
                     b_ui + l * 128, ln_i_g + (l < 2 ? l : 0) * 128, ln_i_b + (l < 2 ? l : 0) * 128,
                     hi_n, (l < 2) ? hi16 : nullptr, nullptr, NII, mode};
        GemmP lu_ = {hu_n, wm[9 + l], wm[9 + l] + 16384, hu_c, wm[12 + l], wm[12 + l] + 16384,
                     b_iu + l * 128, ln_u_g + (l < 2 ? l : 0) * 128, ln_u_b + (l < 2 ? l : 0) * 128,
                     hu_n, (l < 2) ? hu16 : nullptr, nullptr, NUU, mode};
        gemm_dual<<<GB_I + GB_U, 256, 0, stream>>>(li_, lu_, GB_I, nullptr, nullptr, nullptr, nullptr);
        float* t;
        t = hu_c; hu_c = hu_n; hu_n = t;
        t = hi_c; hi_c = hi_n; hi_n = t;
    }
}